// Round 1
// baseline (131.124 us; speedup 1.0000x reference)
//
#include <hip/hip_runtime.h>
#include <float.h>

#define NB    16
#define CIN   64
#define NPT   16384
#define NRING 16
#define MAXR  1520
#define CNT   1024
#define LTOT  (NRING*MAXR)   // 24320
#define MBLK  380            // LTOT/64
#define NCH   128
#define NBLK1 (NB*CIN)       // 1024

// K1: block = (b, cp) with cp = l%64 channel-slot. Stage x[b][cp][:] (64KB) in LDS.
// Thread t = (g = t&15, r = t>>4): computes y[b, g*8+o, m*64+cp] for all m in ring r,
// accumulating ring max/min + channel sum/sumsq in registers. Deterministic, no atomics.
__global__ __launch_bounds__(256) void k1_gather_conv(
    const float* __restrict__ x, const float* __restrict__ Wg,
    const float* __restrict__ bias, const int* __restrict__ choice,
    float* __restrict__ p_sum, float* __restrict__ p_sqs,
    float* __restrict__ p_max, float* __restrict__ p_min)
{
    __shared__ float xrow[NPT];   // 64 KB
    const int blk = blockIdx.x;
    const int b  = blk >> 6;
    const int cp = blk & 63;

    // coalesced stage: 16384 floats, 16 float4 per thread
    {
        const float4* src = (const float4*)(x + ((size_t)(b*CIN + cp)) * NPT);
        float4* dst = (float4*)xrow;
        #pragma unroll
        for (int i = 0; i < NPT/4/256; ++i)
            dst[threadIdx.x + i*256] = src[threadIdx.x + i*256];
    }
    __syncthreads();

    const int t = threadIdx.x;
    const int g = t & 15;
    const int r = t >> 4;

    float w[8][4], bs[8];
    #pragma unroll
    for (int o = 0; o < 8; ++o) {
        bs[o] = bias[g*8+o];
        #pragma unroll
        for (int c = 0; c < 4; ++c) w[o][c] = Wg[(g*8+o)*4 + c];
    }

    const int* __restrict__ chb = choice + ((size_t)b*NRING + g) * MAXR;
    const float* __restrict__ xg = xrow + g*CNT;

    // m-range of ring r for this cp: partition of [0,380)
    int mlo = (r*MAXR - cp + 63) >> 6;
    int mhi = ((r+1)*MAXR - cp + 63) >> 6;
    if (mhi > MBLK) mhi = MBLK;

    float smax[8], smin[8], ssum[8], ssq[8];
    #pragma unroll
    for (int o = 0; o < 8; ++o) { smax[o] = -FLT_MAX; smin[o] = FLT_MAX; ssum[o] = 0.f; ssq[o] = 0.f; }

    for (int m = mlo; m < mhi; ++m) {
        float v0 = xg[chb[m]];
        float v1 = xg[chb[m + MBLK]];
        float v2 = xg[chb[m + 2*MBLK]];
        float v3 = xg[chb[m + 3*MBLK]];
        #pragma unroll
        for (int o = 0; o < 8; ++o) {
            float y = fmaf(w[o][0], v0, fmaf(w[o][1], v1,
                      fmaf(w[o][2], v2, fmaf(w[o][3], v3, bs[o]))));
            smax[o] = fmaxf(smax[o], y);
            smin[o] = fminf(smin[o], y);
            ssum[o] += y;
            ssq[o]  = fmaf(y, y, ssq[o]);
        }
    }

    // per-block ring partials: [blk][ch][r], ch = g*8+o  (written unconditionally)
    #pragma unroll
    for (int o = 0; o < 8; ++o) {
        size_t cell = (size_t)blk*2048 + (size_t)((g*8+o)*16 + r);
        p_max[cell] = smax[o];
        p_min[cell] = smin[o];
    }

    // channel-sum reduce across the 16 r-threads sharing g (reuse xrow as scratch)
    __syncthreads();
    float* redS = xrow;          // 256*9 padded
    float* redQ = xrow + 2304;
    #pragma unroll
    for (int o = 0; o < 8; ++o) { redS[t*9+o] = ssum[o]; redQ[t*9+o] = ssq[o]; }
    __syncthreads();
    if (t < NCH) {
        const int gg = t >> 3, oo = t & 7;
        float S = 0.f, Q = 0.f;
        #pragma unroll
        for (int rr = 0; rr < 16; ++rr) {
            S += redS[(rr*16+gg)*9 + oo];
            Q += redQ[(rr*16+gg)*9 + oo];
        }
        p_sum[(size_t)blk*NCH + t] = S;
        p_sqs[(size_t)blk*NCH + t] = Q;
    }
}

// K2a: per-channel mean / inv-std from 1024 block partials (deterministic tree)
__global__ __launch_bounds__(256) void k2a_stats(
    const float* __restrict__ p_sum, const float* __restrict__ p_sqs,
    float2* __restrict__ stats)
{
    __shared__ float lsum[256], lsq[256];
    const int ch = blockIdx.x;
    float S = 0.f, Q = 0.f;
    for (int j = threadIdx.x; j < NBLK1; j += 256) {
        S += p_sum[(size_t)j*NCH + ch];
        Q += p_sqs[(size_t)j*NCH + ch];
    }
    lsum[threadIdx.x] = S; lsq[threadIdx.x] = Q;
    __syncthreads();
    for (int s = 128; s > 0; s >>= 1) {
        if (threadIdx.x < s) {
            lsum[threadIdx.x] += lsum[threadIdx.x + s];
            lsq[threadIdx.x]  += lsq[threadIdx.x + s];
        }
        __syncthreads();
    }
    if (threadIdx.x == 0) {
        const float inv = 1.0f / (float)((size_t)NB * LTOT);
        float mean = lsum[0] * inv;
        float var  = lsq[0] * inv - mean*mean;
        stats[ch] = make_float2(mean, rsqrtf(var + 1e-5f));
    }
}

// K2b: reduce the 64 cp-partials per (b,ch,r) and apply the BN affine (max if gamma>=0, min else)
__global__ __launch_bounds__(256) void k2b_pool(
    const float* __restrict__ p_max, const float* __restrict__ p_min,
    const float2* __restrict__ stats, const float* __restrict__ gamma,
    const float* __restrict__ beta, float* __restrict__ pooled)
{
    const int cell = blockIdx.x*256 + threadIdx.x;   // [0, 32768)
    const int b   = cell >> 11;
    const int chr = cell & 2047;                     // ch*16 + r
    const int ch  = chr >> 4;
    float mx = -FLT_MAX, mn = FLT_MAX;
    for (int cp = 0; cp < 64; ++cp) {
        size_t base = ((size_t)(b*64 + cp))*2048 + (size_t)chr;
        mx = fmaxf(mx, p_max[base]);
        mn = fminf(mn, p_min[base]);
    }
    const float2 st = stats[ch];
    const float gm = gamma[ch];
    const float raw = (gm >= 0.0f) ? mx : mn;
    pooled[cell] = gm * (raw - st.x) * st.y + beta[ch];
}

// K3: broadcast pooled [B][128][16] -> out [B][128][16384], float4 stores
__global__ __launch_bounds__(256) void k3_bcast(
    const float* __restrict__ pooled, float4* __restrict__ out)
{
    const int total4 = NB*NCH*(NPT/4);               // 8388608
    const int stride = gridDim.x * blockDim.x;
    for (int i = blockIdx.x*blockDim.x + threadIdx.x; i < total4; i += stride) {
        const int n4 = i & (NPT/4 - 1);              // 4096 float4 per (b,ch)
        const int bc = i >> 12;
        const int rr = n4 >> 8;                      // ring = (n4*4)/1024
        const float v = pooled[bc*NRING + rr];
        out[i] = make_float4(v, v, v, v);
    }
}

extern "C" void kernel_launch(void* const* d_in, const int* in_sizes, int n_in,
                              void* d_out, int out_size, void* d_ws, size_t ws_size,
                              hipStream_t stream)
{
    const float* x     = (const float*)d_in[0];
    const float* Wg    = (const float*)d_in[1];
    const float* bias  = (const float*)d_in[2];
    const float* gamma = (const float*)d_in[3];
    const float* beta  = (const float*)d_in[4];
    // d_in[5] = ring (deterministic arange//cnt, unused)
    const int* choice  = (const int*)d_in[6];

    float* p_sum = (float*)d_ws;                          // 1024*128
    float* p_sqs = p_sum + (size_t)NBLK1*NCH;             // 1024*128
    float* p_max = p_sqs + (size_t)NBLK1*NCH;             // 1024*2048
    float* p_min = p_max + (size_t)NBLK1*2048;            // 1024*2048
    float2* stats = (float2*)(p_min + (size_t)NBLK1*2048);// 128
    float* pooled = (float*)(stats + NCH);                // 32768
    // total ws use ≈ 18 MB

    k1_gather_conv<<<NBLK1, 256, 0, stream>>>(x, Wg, bias, choice, p_sum, p_sqs, p_max, p_min);
    k2a_stats<<<NCH, 256, 0, stream>>>(p_sum, p_sqs, stats);
    k2b_pool<<<(NB*NCH*NRING)/256, 256, 0, stream>>>(p_max, p_min, stats, gamma, beta, pooled);
    k3_bcast<<<2048, 256, 0, stream>>>(pooled, (float4*)d_out);
}

// Round 2
// 95.255 us; speedup vs baseline: 1.3766x; 1.3766x over previous
//
#include <hip/hip_runtime.h>
#include <float.h>

#define NB    16
#define CIN   64
#define NPT   16384
#define NRING 16
#define MAXR  1520
#define CNT   1024
#define LTOT  (NRING*MAXR)   // 24320
#define MBLK  380            // LTOT/64
#define NCH   128
#define NBLK1 (NB*CIN)       // 1024

// K1: block = (b, cp) with cp = l%64. Stage x[b][cp][:] (64KB) in LDS.
// 512 threads: s = t&1 (m-split), g = (t>>1)&15 (group), r = t>>5 (ring).
// Each thread covers m = mlo+s, mlo+s+2, ... of ring r for group g.
// Adjacent lanes (s=0,1) read consecutive choice entries (8B coalesced).
__global__ __launch_bounds__(512) void k1_gather_conv(
    const float* __restrict__ x, const float* __restrict__ Wg,
    const float* __restrict__ bias, const int* __restrict__ choice,
    float* __restrict__ p_sum, float* __restrict__ p_sqs,
    float* __restrict__ p_max, float* __restrict__ p_min)
{
    __shared__ float xrow[NPT];   // 64 KB, reused as reduction scratch later
    const int blk = blockIdx.x;
    const int b  = blk >> 6;
    const int cp = blk & 63;

    // coalesced stage: 16384 floats = 4096 float4, 8 per thread
    {
        const float4* src = (const float4*)(x + ((size_t)(b*CIN + cp)) * NPT);
        float4* dst = (float4*)xrow;
        #pragma unroll
        for (int i = 0; i < NPT/4/512; ++i)
            dst[threadIdx.x + i*512] = src[threadIdx.x + i*512];
    }
    __syncthreads();

    const int t = threadIdx.x;
    const int s = t & 1;
    const int g = (t >> 1) & 15;
    const int r = t >> 5;

    float w[8][4], bs[8];
    #pragma unroll
    for (int o = 0; o < 8; ++o) {
        bs[o] = bias[g*8+o];
        #pragma unroll
        for (int c = 0; c < 4; ++c) w[o][c] = Wg[(g*8+o)*4 + c];
    }

    const int* __restrict__ chb = choice + ((size_t)b*NRING + g) * MAXR;
    const float* __restrict__ xg = xrow + g*CNT;

    // m-range of ring r for this cp
    int mlo = (r*MAXR - cp + 63) >> 6;
    int mhi = ((r+1)*MAXR - cp + 63) >> 6;
    if (mhi > MBLK) mhi = MBLK;

    float smax[8], smin[8], ssum[8], ssq[8];
    #pragma unroll
    for (int o = 0; o < 8; ++o) { smax[o] = -FLT_MAX; smin[o] = FLT_MAX; ssum[o] = 0.f; ssq[o] = 0.f; }

    int m = mlo + s;
    int i0=0, i1=0, i2=0, i3=0;
    if (m < mhi) {
        i0 = chb[m]; i1 = chb[m + MBLK]; i2 = chb[m + 2*MBLK]; i3 = chb[m + 3*MBLK];
    }
    while (m < mhi) {
        const int mn = m + 2;
        int j0=0, j1=0, j2=0, j3=0;
        if (mn < mhi) {   // prefetch next iteration's indices
            j0 = chb[mn]; j1 = chb[mn + MBLK]; j2 = chb[mn + 2*MBLK]; j3 = chb[mn + 3*MBLK];
        }
        const float v0 = xg[i0];
        const float v1 = xg[i1];
        const float v2 = xg[i2];
        const float v3 = xg[i3];
        #pragma unroll
        for (int o = 0; o < 8; ++o) {
            float y = fmaf(w[o][0], v0, fmaf(w[o][1], v1,
                      fmaf(w[o][2], v2, fmaf(w[o][3], v3, bs[o]))));
            smax[o] = fmaxf(smax[o], y);
            smin[o] = fminf(smin[o], y);
            ssum[o] += y;
            ssq[o]  = fmaf(y, y, ssq[o]);
        }
        m = mn; i0 = j0; i1 = j1; i2 = j2; i3 = j3;
    }

    // combine the two s-copies (adjacent lanes) — deterministic
    #pragma unroll
    for (int o = 0; o < 8; ++o) {
        smax[o] = fmaxf(smax[o], __shfl_xor(smax[o], 1));
        smin[o] = fminf(smin[o], __shfl_xor(smin[o], 1));
        ssum[o] += __shfl_xor(ssum[o], 1);
        ssq[o]  += __shfl_xor(ssq[o], 1);
    }

    // ring partials, layout [blk][r][ch]: coalesced float4 stores by even lanes
    if (s == 0) {
        float* base = p_max + ((size_t)blk*NRING + r)*NCH + g*8;
        float* base2 = p_min + ((size_t)blk*NRING + r)*NCH + g*8;
        ((float4*)base)[0]  = make_float4(smax[0], smax[1], smax[2], smax[3]);
        ((float4*)base)[1]  = make_float4(smax[4], smax[5], smax[6], smax[7]);
        ((float4*)base2)[0] = make_float4(smin[0], smin[1], smin[2], smin[3]);
        ((float4*)base2)[1] = make_float4(smin[4], smin[5], smin[6], smin[7]);
    }

    // channel sum/sumsq block reduction (reuse xrow as scratch, padded stride 17)
    __syncthreads();
    float* redS = xrow;                 // 128*17 = 2176 floats
    float* redQ = xrow + 2184;
    if (s == 0) {
        #pragma unroll
        for (int o = 0; o < 8; ++o) {
            redS[(g*8+o)*17 + r] = ssum[o];
            redQ[(g*8+o)*17 + r] = ssq[o];
        }
    }
    __syncthreads();
    if (t < NCH) {
        float S = 0.f, Q = 0.f;
        #pragma unroll
        for (int rr = 0; rr < 16; ++rr) {
            S += redS[t*17 + rr];
            Q += redQ[t*17 + rr];
        }
        p_sum[(size_t)blk*NCH + t] = S;
        p_sqs[(size_t)blk*NCH + t] = Q;
    }
}

// K2a: per-channel mean / inv-std from 1024 block partials (deterministic tree)
__global__ __launch_bounds__(256) void k2a_stats(
    const float* __restrict__ p_sum, const float* __restrict__ p_sqs,
    float2* __restrict__ stats)
{
    __shared__ float lsum[256], lsq[256];
    const int ch = blockIdx.x;
    float S = 0.f, Q = 0.f;
    for (int j = threadIdx.x; j < NBLK1; j += 256) {
        S += p_sum[(size_t)j*NCH + ch];
        Q += p_sqs[(size_t)j*NCH + ch];
    }
    lsum[threadIdx.x] = S; lsq[threadIdx.x] = Q;
    __syncthreads();
    for (int sred = 128; sred > 0; sred >>= 1) {
        if (threadIdx.x < sred) {
            lsum[threadIdx.x] += lsum[threadIdx.x + sred];
            lsq[threadIdx.x]  += lsq[threadIdx.x + sred];
        }
        __syncthreads();
    }
    if (threadIdx.x == 0) {
        const float inv = 1.0f / (float)((size_t)NB * LTOT);
        float mean = lsum[0] * inv;
        float var  = lsq[0] * inv - mean*mean;
        stats[ch] = make_float2(mean, rsqrtf(var + 1e-5f));
    }
}

// K2b: reduce the 64 cp-partials per (b,r,ch), apply BN affine (max if gamma>=0 else min)
__global__ __launch_bounds__(256) void k2b_pool(
    const float* __restrict__ p_max, const float* __restrict__ p_min,
    const float2* __restrict__ stats, const float* __restrict__ gamma,
    const float* __restrict__ beta, float* __restrict__ pooled)
{
    const int cell = blockIdx.x*256 + threadIdx.x;   // [0, 32768) = b*2048 + r*128 + ch
    const int b  = cell >> 11;
    const int rc = cell & 2047;
    const int r  = rc >> 7;
    const int ch = rc & 127;
    float mx = -FLT_MAX, mn = FLT_MAX;
    for (int cpi = 0; cpi < 64; ++cpi) {
        size_t base = (((size_t)(b*64 + cpi))*NRING + r)*NCH + ch;
        mx = fmaxf(mx, p_max[base]);
        mn = fminf(mn, p_min[base]);
    }
    const float2 st = stats[ch];
    const float gm = gamma[ch];
    const float raw = (gm >= 0.0f) ? mx : mn;
    pooled[(b*NCH + ch)*NRING + r] = gm * (raw - st.x) * st.y + beta[ch];
}

// K3: broadcast pooled [B][128][16] -> out [B][128][16384], float4 stores
__global__ __launch_bounds__(256) void k3_bcast(
    const float* __restrict__ pooled, float4* __restrict__ out)
{
    const int total4 = NB*NCH*(NPT/4);               // 8388608
    const int stride = gridDim.x * blockDim.x;
    for (int i = blockIdx.x*blockDim.x + threadIdx.x; i < total4; i += stride) {
        const int n4 = i & (NPT/4 - 1);              // 4096 float4 per (b,ch)
        const int bc = i >> 12;
        const int rr = n4 >> 8;                      // ring = (n4*4)/1024
        const float v = pooled[bc*NRING + rr];
        out[i] = make_float4(v, v, v, v);
    }
}

extern "C" void kernel_launch(void* const* d_in, const int* in_sizes, int n_in,
                              void* d_out, int out_size, void* d_ws, size_t ws_size,
                              hipStream_t stream)
{
    const float* x     = (const float*)d_in[0];
    const float* Wg    = (const float*)d_in[1];
    const float* bias  = (const float*)d_in[2];
    const float* gamma = (const float*)d_in[3];
    const float* beta  = (const float*)d_in[4];
    // d_in[5] = ring (deterministic arange//cnt, unused)
    const int* choice  = (const int*)d_in[6];

    float* p_sum = (float*)d_ws;                          // 1024*128
    float* p_sqs = p_sum + (size_t)NBLK1*NCH;             // 1024*128
    float* p_max = p_sqs + (size_t)NBLK1*NCH;             // 1024*2048
    float* p_min = p_max + (size_t)NBLK1*2048;            // 1024*2048
    float2* stats = (float2*)(p_min + (size_t)NBLK1*2048);// 128
    float* pooled = (float*)(stats + NCH);                // 32768

    k1_gather_conv<<<NBLK1, 512, 0, stream>>>(x, Wg, bias, choice, p_sum, p_sqs, p_max, p_min);
    k2a_stats<<<NCH, 256, 0, stream>>>(p_sum, p_sqs, stats);
    k2b_pool<<<(NB*NCH*NRING)/256, 256, 0, stream>>>(p_max, p_min, stats, gamma, beta, pooled);
    k3_bcast<<<2048, 256, 0, stream>>>(pooled, (float4*)d_out);
}

// Round 3
// 70.784 us; speedup vs baseline: 1.8525x; 1.3457x over previous
//
#include <hip/hip_runtime.h>
#include <float.h>

#define NB    16
#define CIN   64
#define NPT   16384
#define NRING 16
#define MAXR  1520
#define CNT   1024
#define LTOT  (NRING*MAXR)   // 24320
#define MBLK  380            // LTOT/64
#define NCH   128
#define NBLK1 (NB*CIN*2)     // 2048 blocks for K1 (b, cp, h)
#define IDXSTRIDE 500        // 496 rounded to bank-spreading stride (500%32=20 -> 8 distinct banks over g8)

// K1: block = (b, cp, h). h selects 8 of the 16 conv groups (= input rings).
// LDS: xs = x[b][cp][h*8192 .. +8192] (32KB, ring-rotated swizzle),
//      ilds = choice[b][g][1024:1520] for the 8 groups (16KB).
// Inner loop is 100% LDS+VALU: identity positions (p<1024) need no index.
// Threads 512: s = t&3 (m-split), g8 = (t>>2)&7 (local group), r = t>>5 (output ring).
__global__ __launch_bounds__(512) void k1_gather_conv(
    const float* __restrict__ x, const float* __restrict__ Wg,
    const float* __restrict__ bias, const int* __restrict__ choice,
    float* __restrict__ p_sum, float* __restrict__ p_sqs,
    float* __restrict__ p_max, float* __restrict__ p_min)
{
    __shared__ float xs[8192];       // 32 KB
    __shared__ int   ilds[8*IDXSTRIDE]; // 16 KB

    const int blk = blockIdx.x;
    const int b  = blk >> 7;
    const int cp = (blk >> 1) & 63;
    const int h  = blk & 1;
    const int t  = threadIdx.x;

    // stage x half-row with per-ring rotation: ring g8 chunk j -> chunk ((j+g8)&255)
    {
        const float4* src = (const float4*)(x + ((size_t)(b*CIN + cp)) * NPT + h*8192);
        float4* dst = (float4*)xs;
        #pragma unroll
        for (int i = 0; i < 4; ++i) {
            const int J  = t + i*512;          // [0,2048)
            const int g8 = J >> 8;
            const int j  = J & 255;
            dst[(g8 << 8) + ((j + g8) & 255)] = src[J];
        }
    }
    // stage random choice tail: ring g8 -> ilds[g8*IDXSTRIDE + 0..495]
    {
        #pragma unroll
        for (int i = 0; i < 2; ++i) {
            const int J  = t + i*512;          // [0,1024); 128 int4-slots per ring
            const int g8 = J >> 7;
            const int j  = J & 127;
            if (j < 124) {
                const int4 v = *(const int4*)(choice + ((size_t)(b*NRING + h*8 + g8))*MAXR + 1024 + j*4);
                *(int4*)(ilds + g8*IDXSTRIDE + j*4) = v;
            }
        }
    }
    __syncthreads();

    const int s  = t & 3;
    const int g8 = (t >> 2) & 7;
    const int r  = t >> 5;
    const int g  = h*8 + g8;

    float w[8][4], bs[8];
    #pragma unroll
    for (int o = 0; o < 8; ++o) {
        bs[o] = bias[g*8+o];
        #pragma unroll
        for (int c = 0; c < 4; ++c) w[o][c] = Wg[(g*8+o)*4 + c];
    }

    // m-range of output ring r for this cp
    int mlo = (r*MAXR - cp + 63) >> 6;
    int mhi = ((r+1)*MAXR - cp + 63) >> 6;
    if (mhi > MBLK) mhi = MBLK;

    float smax[8], smin[8], ssum[8], ssq[8];
    #pragma unroll
    for (int o = 0; o < 8; ++o) { smax[o] = -FLT_MAX; smin[o] = FLT_MAX; ssum[o] = 0.f; ssq[o] = 0.f; }

    const int rot = g8 << 2;                       // 4*g8 rotation
    const float* __restrict__ xg = xs + (g8 << 10);
    const int*   __restrict__ ig = ilds + g8*IDXSTRIDE;

    for (int m = mlo + s; m < mhi; m += 4) {
        // c=0,1: identity. c=2: identity iff m<264. c=3: always random.
        const int off2 = (m >= 264) ? (m - 264) : 0;     // clamped safe read
        const int lidx2 = ig[off2];
        const int idx2 = (m < 264) ? (760 + m) : lidx2;
        const int idx3 = ig[116 + m];
        const float v0 = xg[( m        + rot) & 1023];
        const float v1 = xg[((380 + m) + rot) & 1023];
        const float v2 = xg[( idx2     + rot) & 1023];
        const float v3 = xg[( idx3     + rot) & 1023];
        #pragma unroll
        for (int o = 0; o < 8; ++o) {
            float y = fmaf(w[o][0], v0, fmaf(w[o][1], v1,
                      fmaf(w[o][2], v2, fmaf(w[o][3], v3, bs[o]))));
            smax[o] = fmaxf(smax[o], y);
            smin[o] = fminf(smin[o], y);
            ssum[o] += y;
            ssq[o]  = fmaf(y, y, ssq[o]);
        }
    }

    // combine the four s-copies (adjacent lanes) — deterministic
    #pragma unroll
    for (int o = 0; o < 8; ++o) {
        smax[o] = fmaxf(smax[o], __shfl_xor(smax[o], 1));
        smin[o] = fminf(smin[o], __shfl_xor(smin[o], 1));
        ssum[o] += __shfl_xor(ssum[o], 1);
        ssq[o]  += __shfl_xor(ssq[o], 1);
        smax[o] = fmaxf(smax[o], __shfl_xor(smax[o], 2));
        smin[o] = fminf(smin[o], __shfl_xor(smin[o], 2));
        ssum[o] += __shfl_xor(ssum[o], 2);
        ssq[o]  += __shfl_xor(ssq[o], 2);
    }

    // ring partials, layout [b*64+cp][r][128ch], this block owns ch = h*64 + g8*8 + o
    if (s == 0) {
        float* base  = p_max + (((size_t)(b*64 + cp))*NRING + r)*NCH + h*64 + g8*8;
        float* base2 = p_min + (((size_t)(b*64 + cp))*NRING + r)*NCH + h*64 + g8*8;
        ((float4*)base)[0]  = make_float4(smax[0], smax[1], smax[2], smax[3]);
        ((float4*)base)[1]  = make_float4(smax[4], smax[5], smax[6], smax[7]);
        ((float4*)base2)[0] = make_float4(smin[0], smin[1], smin[2], smin[3]);
        ((float4*)base2)[1] = make_float4(smin[4], smin[5], smin[6], smin[7]);
    }

    // channel sum/sumsq block reduction over the 16 r's (reuse xs as scratch)
    __syncthreads();
    float* redS = xs;                 // 64*17 floats
    float* redQ = xs + 1100;
    if (s == 0) {
        #pragma unroll
        for (int o = 0; o < 8; ++o) {
            redS[(g8*8+o)*17 + r] = ssum[o];
            redQ[(g8*8+o)*17 + r] = ssq[o];
        }
    }
    __syncthreads();
    if (t < 64) {
        float S = 0.f, Q = 0.f;
        #pragma unroll
        for (int rr = 0; rr < 16; ++rr) {
            S += redS[t*17 + rr];
            Q += redQ[t*17 + rr];
        }
        p_sum[(size_t)blk*64 + t] = S;   // [2048][64], ch = h*64 + t
        p_sqs[(size_t)blk*64 + t] = Q;
    }
}

// K2a: per-channel mean / inv-std from 2048x64 block partials (deterministic tree)
__global__ __launch_bounds__(256) void k2a_stats(
    const float* __restrict__ p_sum, const float* __restrict__ p_sqs,
    float2* __restrict__ stats)
{
    __shared__ float lsum[256], lsq[256];
    const int ch = blockIdx.x;
    const int hh = ch >> 6, c64 = ch & 63;
    float S = 0.f, Q = 0.f;
    for (int j = threadIdx.x; j < 1024; j += 256) {
        S += p_sum[(size_t)j*128 + hh*64 + c64];
        Q += p_sqs[(size_t)j*128 + hh*64 + c64];
    }
    lsum[threadIdx.x] = S; lsq[threadIdx.x] = Q;
    __syncthreads();
    for (int sred = 128; sred > 0; sred >>= 1) {
        if (threadIdx.x < sred) {
            lsum[threadIdx.x] += lsum[threadIdx.x + sred];
            lsq[threadIdx.x]  += lsq[threadIdx.x + sred];
        }
        __syncthreads();
    }
    if (threadIdx.x == 0) {
        const float inv = 1.0f / (float)((size_t)NB * LTOT);
        float mean = lsum[0] * inv;
        float var  = lsq[0] * inv - mean*mean;
        stats[ch] = make_float2(mean, rsqrtf(var + 1e-5f));
    }
}

// K2b: reduce the 64 cp-partials per (b,r,ch), apply BN affine (max if gamma>=0 else min)
__global__ __launch_bounds__(256) void k2b_pool(
    const float* __restrict__ p_max, const float* __restrict__ p_min,
    const float2* __restrict__ stats, const float* __restrict__ gamma,
    const float* __restrict__ beta, float* __restrict__ pooled)
{
    const int cell = blockIdx.x*256 + threadIdx.x;   // b*2048 + r*128 + ch
    const int b  = cell >> 11;
    const int rc = cell & 2047;
    const int r  = rc >> 7;
    const int ch = rc & 127;
    float mx = -FLT_MAX, mn = FLT_MAX;
    for (int cpi = 0; cpi < 64; ++cpi) {
        size_t base = (((size_t)(b*64 + cpi))*NRING + r)*NCH + ch;
        mx = fmaxf(mx, p_max[base]);
        mn = fminf(mn, p_min[base]);
    }
    const float2 st = stats[ch];
    const float gm = gamma[ch];
    const float raw = (gm >= 0.0f) ? mx : mn;
    pooled[(b*NCH + ch)*NRING + r] = gm * (raw - st.x) * st.y + beta[ch];
}

// K3: broadcast pooled [B][128][16] -> out [B][128][16384], float4 stores
__global__ __launch_bounds__(256) void k3_bcast(
    const float* __restrict__ pooled, float4* __restrict__ out)
{
    const int total4 = NB*NCH*(NPT/4);               // 8388608
    const int stride = gridDim.x * blockDim.x;
    for (int i = blockIdx.x*blockDim.x + threadIdx.x; i < total4; i += stride) {
        const int n4 = i & (NPT/4 - 1);
        const int bc = i >> 12;
        const int rr = n4 >> 8;
        const float v = pooled[bc*NRING + rr];
        out[i] = make_float4(v, v, v, v);
    }
}

extern "C" void kernel_launch(void* const* d_in, const int* in_sizes, int n_in,
                              void* d_out, int out_size, void* d_ws, size_t ws_size,
                              hipStream_t stream)
{
    const float* x     = (const float*)d_in[0];
    const float* Wg    = (const float*)d_in[1];
    const float* bias  = (const float*)d_in[2];
    const float* gamma = (const float*)d_in[3];
    const float* beta  = (const float*)d_in[4];
    const int* choice  = (const int*)d_in[6];

    float* p_sum = (float*)d_ws;                           // 2048*64
    float* p_sqs = p_sum + (size_t)2048*64;                // 2048*64
    float* p_max = p_sqs + (size_t)2048*64;                // 1024*16*128
    float* p_min = p_max + (size_t)1024*NRING*NCH;         // 1024*16*128
    float2* stats = (float2*)(p_min + (size_t)1024*NRING*NCH); // 128
    float* pooled = (float*)(stats + NCH);                 // 32768

    k1_gather_conv<<<NBLK1, 512, 0, stream>>>(x, Wg, bias, choice, p_sum, p_sqs, p_max, p_min);
    k2a_stats<<<NCH, 256, 0, stream>>>(p_sum, p_sqs, stats);
    k2b_pool<<<(NB*NCH*NRING)/256, 256, 0, stream>>>(p_max, p_min, stats, gamma, beta, pooled);
    k3_bcast<<<2048, 256, 0, stream>>>(pooled, (float4*)d_out);
}